// Round 1
// baseline (669.249 us; speedup 1.0000x reference)
//
#include <hip/hip_runtime.h>
#include <cstdint>
#include <cstddef>

// Problem constants: V=32000 D=1024 T=1024 H=16 HD=64 B=4
// ws layout (bytes), total ~126.4 MB:
//   xb     @ 0          8,388,608   x bf16 [4096][1024]  (reused as h2)
//   wqkvT  @ 8388608    6,291,456   [3072][1024] bf16 (n = p*1024+h*64+e, k=d)
//   w1T    @ 14680064   2,097,152
//   w2T    @ 16777216   2,097,152
//   woutT  @ 18874368   65,536,000  [32000][1024] bf16
//   qbuf   @ 84410368   8,388,608   [B,H,T,64] bf16
//   kbuf   @ 92798976   8,388,608
//   vbuf   @ 101187584  8,388,608
//   attx   @ 109576192  8,388,608   [4096][1024] bf16
//   h1     @ 117964800  8,388,608

#define DEV __device__ __forceinline__

typedef __attribute__((ext_vector_type(8))) short bf16x8;   // 8 bf16 = 4 VGPRs
typedef __attribute__((ext_vector_type(4))) float f32x4;

DEV unsigned short f2bf(float f) {           // f32 -> bf16 RNE
  unsigned u = __float_as_uint(f);
  u = (u + 0x7fffu + ((u >> 16) & 1u)) >> 16;
  return (unsigned short)u;
}

DEV void stage16(const void* g, void* l) {   // async global->LDS, 16B/lane
  __builtin_amdgcn_global_load_lds(
      (const __attribute__((address_space(1))) unsigned int*)g,
      (__attribute__((address_space(3))) unsigned int*)l, 16, 0, 0);
}

// ---------------- embed: x = tok_emb[idx] + pos_emb, cast bf16 --------------
__global__ __launch_bounds__(256) void k_embed(
    const int* __restrict__ idx, const float* __restrict__ tok,
    const float* __restrict__ pos, unsigned short* __restrict__ xb) {
  int i = blockIdx.x * 256 + threadIdx.x;   // over 4096*1024/4 float4 groups
  int row = i >> 8;                         // b*T + t   (256 float4 per row)
  int c4 = i & 255;
  int t = row & 1023;
  int tokid = idx[row];
  const float4 a = ((const float4*)tok)[(size_t)tokid * 256 + c4];
  const float4 p = ((const float4*)pos)[(size_t)t * 256 + c4];
  ushort4 o;
  o.x = f2bf(a.x + p.x); o.y = f2bf(a.y + p.y);
  o.z = f2bf(a.z + p.z); o.w = f2bf(a.w + p.w);
  ((ushort4*)xb)[i] = o;
}

// -------- pack Wq/Wk/Wv [H,D,HD] f32 -> wqkvT [3072][1024] bf16 -------------
__global__ __launch_bounds__(256) void k_pack_qkv(
    const float* __restrict__ Wq, const float* __restrict__ Wk,
    const float* __restrict__ Wv, unsigned short* __restrict__ out) {
  __shared__ float tile[64][65];
  int blk = blockIdx.x;                 // p*256 + h*16 + dblk
  int p = blk >> 8, h = (blk >> 4) & 15, d0 = (blk & 15) * 64;
  const float* W = (p == 0) ? Wq : ((p == 1) ? Wk : Wv);
  int tid = threadIdx.x, rq = tid >> 6, cc = tid & 63;
#pragma unroll
  for (int it = 0; it < 16; ++it) {
    int dr = it * 4 + rq;
    tile[dr][cc] = W[((size_t)h * 1024 + d0 + dr) * 64 + cc];   // coalesced
  }
  __syncthreads();
#pragma unroll
  for (int it = 0; it < 16; ++it) {
    int e = it * 4 + rq;
    out[((size_t)(p * 1024 + h * 64 + e)) * 1024 + d0 + cc] = f2bf(tile[cc][e]);
  }
}

// -------- generic transpose+cast: in f32 [R][C] -> out bf16 [C][R] ----------
__global__ __launch_bounds__(256) void k_transpose(
    const float* __restrict__ in, unsigned short* __restrict__ out,
    int R, int C) {
  __shared__ float tile[64][65];
  int c0 = blockIdx.x * 64, r0 = blockIdx.y * 64;
  int tid = threadIdx.x, rq = tid >> 6, cc = tid & 63;
#pragma unroll
  for (int it = 0; it < 16; ++it) {
    int r = it * 4 + rq;
    tile[r][cc] = in[(size_t)(r0 + r) * C + c0 + cc];
  }
  __syncthreads();
#pragma unroll
  for (int it = 0; it < 16; ++it) {
    int c = it * 4 + rq;
    out[(size_t)(c0 + c) * R + r0 + cc] = f2bf(tile[cc][c]);
  }
}

// ---------------- bf16 MFMA GEMM, m97 structure: C = A * Bt^T ---------------
// A [M][K] bf16 row-major, Bt [N][K] bf16 row-major. 128x128 tile, BK=32,
// 4 waves (2x2), each wave 64x64 = 4x4 frags of 16x16x32.
// EP: 1 = bias+relu -> bf16 [M][N]; 2 = bias -> f32 [M][N];
//     3 = qkv split -> out0/1/2 as [B,H,T,64] bf16 (N must be 3072)
template <int EP>
__global__ __launch_bounds__(256) void k_gemm(
    const unsigned short* __restrict__ A, const unsigned short* __restrict__ Bt,
    const float* __restrict__ bias, void* __restrict__ out0,
    void* __restrict__ out1, void* __restrict__ out2, int M, int N, int K) {
  __shared__ __align__(16) unsigned short As[128 * 32];
  __shared__ __align__(16) unsigned short Bs[128 * 32];
  const int tid = threadIdx.x;
  const int lane = tid & 63, w = tid >> 6;
  const int wr = w >> 1, wc = w & 1;
  const int fr = lane & 15, fg = lane >> 4;
  const int m0 = blockIdx.y * 128, n0 = blockIdx.x * 128;

  f32x4 zero = {0.f, 0.f, 0.f, 0.f};
  f32x4 acc[4][4];
#pragma unroll
  for (int m = 0; m < 4; ++m)
#pragma unroll
    for (int n = 0; n < 4; ++n) acc[m][n] = zero;

  const int c0 = tid, c1 = tid + 256;   // 16B chunks: row=c>>2, koff=(c&3)*8
  const unsigned short* Ab0 = A + (size_t)(m0 + (c0 >> 2)) * K + (c0 & 3) * 8;
  const unsigned short* Ab1 = A + (size_t)(m0 + (c1 >> 2)) * K + (c1 & 3) * 8;
  const unsigned short* Bb0 = Bt + (size_t)(n0 + (c0 >> 2)) * K + (c0 & 3) * 8;
  const unsigned short* Bb1 = Bt + (size_t)(n0 + (c1 >> 2)) * K + (c1 & 3) * 8;
  unsigned short* Ad0 = &As[c0 * 8];
  unsigned short* Ad1 = &As[c1 * 8];
  unsigned short* Bd0 = &Bs[c0 * 8];
  unsigned short* Bd1 = &Bs[c1 * 8];

  for (int k0 = 0; k0 < K; k0 += 32) {
    stage16(Ab0 + k0, Ad0);
    stage16(Ab1 + k0, Ad1);
    stage16(Bb0 + k0, Bd0);
    stage16(Bb1 + k0, Bd1);
    __syncthreads();                       // compiler drains vmcnt here
    bf16x8 af[4], bfv[4];
#pragma unroll
    for (int m = 0; m < 4; ++m)
      af[m] = *(const bf16x8*)&As[(wr * 64 + m * 16 + fr) * 32 + fg * 8];
#pragma unroll
    for (int n = 0; n < 4; ++n)
      bfv[n] = *(const bf16x8*)&Bs[(wc * 64 + n * 16 + fr) * 32 + fg * 8];
#pragma unroll
    for (int m = 0; m < 4; ++m)
#pragma unroll
      for (int n = 0; n < 4; ++n)
        acc[m][n] = __builtin_amdgcn_mfma_f32_16x16x32_bf16(af[m], bfv[n],
                                                            acc[m][n], 0, 0, 0);
    __syncthreads();
  }

#pragma unroll
  for (int m = 0; m < 4; ++m) {
#pragma unroll
    for (int n = 0; n < 4; ++n) {
      const int rb = m0 + wr * 64 + m * 16 + fg * 4;
      const int cc = n0 + wc * 64 + n * 16 + fr;
#pragma unroll
      for (int i = 0; i < 4; ++i) {
        float v = acc[m][n][i];
        const int r = rb + i;
        if (EP == 1) {
          v += bias[cc];
          v = v > 0.f ? v : 0.f;
          ((unsigned short*)out0)[(size_t)r * N + cc] = f2bf(v);
        } else if (EP == 2) {
          v += bias[cc];
          ((float*)out0)[(size_t)r * N + cc] = v;
        } else if (EP == 3) {
          int p = cc >> 10, rem = cc & 1023;
          int h = rem >> 6, e = rem & 63;
          int b = r >> 10, t = r & 1023;
          unsigned short* dst =
              (p == 0) ? (unsigned short*)out0
                       : ((p == 1) ? (unsigned short*)out1 : (unsigned short*)out2);
          dst[(((size_t)(b * 16 + h) * 1024) + t) * 64 + e] = f2bf(v);
        }
      }
    }
  }
}

// ---------------- fused causal flash attention --------------------------------
// q,k,v [B,H,T,64] bf16. Block: 4 waves, Q-tile 64 rows (16/wave), KV tile 64.
// S^T = mfma(K, Q)  -> lane holds q-col = lane&15, kv-row = (lane>>4)*4+i.
// P staged through per-wave LDS to become the PV A-operand.
__global__ __launch_bounds__(256) void k_attn(
    const unsigned short* __restrict__ qb, const unsigned short* __restrict__ kb,
    const unsigned short* __restrict__ vb, unsigned short* __restrict__ attx) {
  __shared__ __align__(16) unsigned short Klds[64][72];  // +8 pad: 16B rows, 2-way max
  __shared__ __align__(16) unsigned short Vt[64][72];    // V transposed [hd][kv]
  __shared__ __align__(16) unsigned short Plds[4][16][72];
  const int qt = blockIdx.x;      // 0..15
  const int bh = blockIdx.y;      // 0..63  (b*16 + h)
  const int tid = threadIdx.x;
  const int w = tid >> 6, lane = tid & 63;
  const int fr = lane & 15, g = lane >> 4;
  const size_t base = (size_t)bh * (1024 * 64);
  const int q0 = qt * 64 + w * 16;
  const int q_abs = q0 + fr;

  bf16x8 qf[2];
#pragma unroll
  for (int t = 0; t < 2; ++t)
    qf[t] = *(const bf16x8*)&qb[base + (size_t)(q0 + fr) * 64 + t * 32 + g * 8];

  f32x4 zero = {0.f, 0.f, 0.f, 0.f};
  f32x4 o[4];
#pragma unroll
  for (int hb = 0; hb < 4; ++hb) o[hb] = zero;
  float m_s = -3.0e38f, l_s = 0.f;

  for (int jt = 0; jt <= qt; ++jt) {
    const int kvb = jt * 64;
#pragma unroll
    for (int it = 0; it < 2; ++it) {       // stage K rows + V transposed
      int c = tid + it * 256;              // 512 chunks of 8 bf16
      int r = c >> 3, e0 = (c & 7) * 8;
      uint4 kd = *(const uint4*)&kb[base + (size_t)(kvb + r) * 64 + e0];
      *(uint4*)&Klds[r][e0] = kd;
      uint4 vd = *(const uint4*)&vb[base + (size_t)(kvb + r) * 64 + e0];
      const unsigned short* vs = (const unsigned short*)&vd;
#pragma unroll
      for (int j = 0; j < 8; ++j) Vt[e0 + j][r] = vs[j];
    }
    __syncthreads();

    f32x4 st[4];
#pragma unroll
    for (int f = 0; f < 4; ++f) {
      st[f] = zero;
#pragma unroll
      for (int t = 0; t < 2; ++t) {
        bf16x8 kf = *(const bf16x8*)&Klds[f * 16 + fr][t * 32 + g * 8];
        st[f] = __builtin_amdgcn_mfma_f32_16x16x32_bf16(kf, qf[t], st[f], 0, 0, 0);
      }
    }
    // mask + online softmax (state per lane for q-row = fr, replicated over g)
    float sv[4][4];
    float tm = -3.0e38f;
#pragma unroll
    for (int f = 0; f < 4; ++f)
#pragma unroll
      for (int i = 0; i < 4; ++i) {
        int kv = kvb + f * 16 + g * 4 + i;
        float s = st[f][i] * 0.125f;       // 1/sqrt(64)
        if (kv > q_abs) s = -3.0e38f;
        sv[f][i] = s;
        tm = fmaxf(tm, s);
      }
    tm = fmaxf(tm, __shfl_xor(tm, 16));
    tm = fmaxf(tm, __shfl_xor(tm, 32));
    float mnew = fmaxf(m_s, tm);
    float scale = expf(m_s - mnew);
    float lsum = 0.f;
#pragma unroll
    for (int f = 0; f < 4; ++f)
#pragma unroll
      for (int i = 0; i < 4; ++i) {
        float pv = expf(sv[f][i] - mnew);
        lsum += pv;
        Plds[w][fr][f * 16 + g * 4 + i] = f2bf(pv);
      }
    lsum += __shfl_xor(lsum, 16);
    lsum += __shfl_xor(lsum, 32);
    l_s = l_s * scale + lsum;
    m_s = mnew;
    // rescale O (O rows live at q' = g*4+i; scale lives at lane q'=fr)
#pragma unroll
    for (int i = 0; i < 4; ++i) {
      float sc = __shfl(scale, g * 4 + i);
#pragma unroll
      for (int hb = 0; hb < 4; ++hb) o[hb][i] *= sc;
    }
    __syncthreads();                       // P visible (and LDS write drain)
#pragma unroll
    for (int t = 0; t < 2; ++t) {
      bf16x8 pf = *(const bf16x8*)&Plds[w][fr][t * 32 + g * 8];
#pragma unroll
      for (int hb = 0; hb < 4; ++hb) {
        bf16x8 vf = *(const bf16x8*)&Vt[hb * 16 + fr][t * 32 + g * 8];
        o[hb] = __builtin_amdgcn_mfma_f32_16x16x32_bf16(pf, vf, o[hb], 0, 0, 0);
      }
    }
    __syncthreads();                       // before next K/V stage
  }

  const float inv = 1.f / l_s;
  const int b = bh >> 4, h = bh & 15;
#pragma unroll
  for (int i = 0; i < 4; ++i) {
    float sc = __shfl(inv, g * 4 + i);
    int trow = q0 + g * 4 + i;
    size_t rowoff = ((size_t)(b * 1024 + trow)) * 1024 + h * 64;
#pragma unroll
    for (int hb = 0; hb < 4; ++hb)
      attx[rowoff + hb * 16 + fr] = f2bf(o[hb][i] * sc);
  }
}

// ------------------------------- launch -------------------------------------
extern "C" void kernel_launch(void* const* d_in, const int* in_sizes, int n_in,
                              void* d_out, int out_size, void* d_ws,
                              size_t ws_size, hipStream_t stream) {
  const int* idx = (const int*)d_in[0];
  const float* tok = (const float*)d_in[1];
  const float* pos = (const float*)d_in[2];
  const float* Wq = (const float*)d_in[3];
  const float* Wk = (const float*)d_in[4];
  const float* Wv = (const float*)d_in[5];
  const float* W1 = (const float*)d_in[6];
  const float* b1 = (const float*)d_in[7];
  const float* W2 = (const float*)d_in[8];
  const float* b2 = (const float*)d_in[9];
  const float* Wout = (const float*)d_in[10];
  const float* bout = (const float*)d_in[11];
  float* out = (float*)d_out;

  char* ws = (char*)d_ws;
  unsigned short* xb    = (unsigned short*)(ws + 0);
  unsigned short* wqkvT = (unsigned short*)(ws + 8388608);
  unsigned short* w1T   = (unsigned short*)(ws + 14680064);
  unsigned short* w2T   = (unsigned short*)(ws + 16777216);
  unsigned short* woutT = (unsigned short*)(ws + 18874368);
  unsigned short* qbuf  = (unsigned short*)(ws + 84410368);
  unsigned short* kbuf  = (unsigned short*)(ws + 92798976);
  unsigned short* vbuf  = (unsigned short*)(ws + 101187584);
  unsigned short* attx  = (unsigned short*)(ws + 109576192);
  unsigned short* h1    = (unsigned short*)(ws + 117964800);
  unsigned short* h2    = xb;   // xb dead after QKV gemm

  k_embed<<<4096, 256, 0, stream>>>(idx, tok, pos, xb);
  k_pack_qkv<<<768, 256, 0, stream>>>(Wq, Wk, Wv, wqkvT);
  k_transpose<<<dim3(16, 16), 256, 0, stream>>>(W1, w1T, 1024, 1024);
  k_transpose<<<dim3(16, 16), 256, 0, stream>>>(W2, w2T, 1024, 1024);
  k_transpose<<<dim3(500, 16), 256, 0, stream>>>(Wout, woutT, 1024, 32000);

  k_gemm<3><<<dim3(24, 32), 256, 0, stream>>>(xb, wqkvT, nullptr, qbuf, kbuf,
                                              vbuf, 4096, 3072, 1024);
  k_attn<<<dim3(16, 64), 256, 0, stream>>>(qbuf, kbuf, vbuf, attx);
  k_gemm<1><<<dim3(8, 32), 256, 0, stream>>>(attx, w1T, b1, h1, nullptr,
                                             nullptr, 4096, 1024, 1024);
  k_gemm<1><<<dim3(8, 32), 256, 0, stream>>>(h1, w2T, b2, h2, nullptr, nullptr,
                                             4096, 1024, 1024);
  k_gemm<2><<<dim3(250, 32), 256, 0, stream>>>(h2, woutT, bout, out, nullptr,
                                               nullptr, 4096, 32000, 1024);
}

// Round 2
// 585.718 us; speedup vs baseline: 1.1426x; 1.1426x over previous
//
#include <hip/hip_runtime.h>
#include <cstdint>
#include <cstddef>

// Problem constants: V=32000 D=1024 T=1024 H=16 HD=64 B=4
// ws layout (bytes):
//   xb     @ 0          8,388,608   x bf16 [4096][1024]  (reused as h2)
//   wqkvT  @ 8388608    6,291,456   [3072][1024] bf16
//   w1T    @ 14680064   2,097,152
//   w2T    @ 16777216   2,097,152
//   woutT  @ 18874368   65,536,000  [32000][1024] bf16
//   qbuf   @ 84410368   8,388,608   [B,H,T,64] bf16
//   kbuf   @ 92798976   8,388,608
//   vbuf   @ 101187584  8,388,608
//   attx   @ 109576192  8,388,608
//   h1     @ 117964800  8,388,608

#define DEV __device__ __forceinline__

typedef __attribute__((ext_vector_type(8))) short bf16x8;
typedef __attribute__((ext_vector_type(4))) float f32x4;

DEV unsigned short f2bf(float f) {
  unsigned u = __float_as_uint(f);
  u = (u + 0x7fffu + ((u >> 16) & 1u)) >> 16;
  return (unsigned short)u;
}

DEV void stage16(const void* g, void* l) {   // async global->LDS, 16B/lane
  __builtin_amdgcn_global_load_lds(
      (const __attribute__((address_space(1))) unsigned int*)g,
      (__attribute__((address_space(3))) unsigned int*)l, 16, 0, 0);
}

// ---------------- embed -----------------------------------------------------
__global__ __launch_bounds__(256) void k_embed(
    const int* __restrict__ idx, const float* __restrict__ tok,
    const float* __restrict__ pos, unsigned short* __restrict__ xb) {
  int i = blockIdx.x * 256 + threadIdx.x;
  int row = i >> 8;
  int c4 = i & 255;
  int t = row & 1023;
  int tokid = idx[row];
  const float4 a = ((const float4*)tok)[(size_t)tokid * 256 + c4];
  const float4 p = ((const float4*)pos)[(size_t)t * 256 + c4];
  ushort4 o;
  o.x = f2bf(a.x + p.x); o.y = f2bf(a.y + p.y);
  o.z = f2bf(a.z + p.z); o.w = f2bf(a.w + p.w);
  ((ushort4*)xb)[i] = o;
}

// -------- pack Wq/Wk/Wv [H,D,HD] f32 -> wqkvT [3072][1024] bf16 -------------
__global__ __launch_bounds__(256) void k_pack_qkv(
    const float* __restrict__ Wq, const float* __restrict__ Wk,
    const float* __restrict__ Wv, unsigned short* __restrict__ out) {
  __shared__ float tile[64][65];
  int blk = blockIdx.x;
  int p = blk >> 8, h = (blk >> 4) & 15, d0 = (blk & 15) * 64;
  const float* W = (p == 0) ? Wq : ((p == 1) ? Wk : Wv);
  int tid = threadIdx.x, rq = tid >> 6, cc = tid & 63;
#pragma unroll
  for (int it = 0; it < 16; ++it) {
    int dr = it * 4 + rq;
    tile[dr][cc] = W[((size_t)h * 1024 + d0 + dr) * 64 + cc];
  }
  __syncthreads();
#pragma unroll
  for (int it = 0; it < 16; ++it) {
    int e = it * 4 + rq;
    out[((size_t)(p * 1024 + h * 64 + e)) * 1024 + d0 + cc] = f2bf(tile[cc][e]);
  }
}

// -------- generic transpose+cast: in f32 [R][C] -> out bf16 [C][R] ----------
__global__ __launch_bounds__(256) void k_transpose(
    const float* __restrict__ in, unsigned short* __restrict__ out,
    int R, int C) {
  __shared__ float tile[64][65];
  int c0 = blockIdx.x * 64, r0 = blockIdx.y * 64;
  int tid = threadIdx.x, rq = tid >> 6, cc = tid & 63;
#pragma unroll
  for (int it = 0; it < 16; ++it) {
    int r = it * 4 + rq;
    tile[r][cc] = in[(size_t)(r0 + r) * C + c0 + cc];
  }
  __syncthreads();
#pragma unroll
  for (int it = 0; it < 16; ++it) {
    int c = it * 4 + rq;
    out[(size_t)(c0 + c) * R + r0 + cc] = f2bf(tile[cc][c]);
  }
}

// ---------------- bf16 MFMA GEMM, m97 structure (used for QKV / FFN) --------
// EP: 1 = bias+relu -> bf16; 3 = qkv split -> [B,H,T,64] bf16 (N=3072)
template <int EP>
__global__ __launch_bounds__(256) void k_gemm(
    const unsigned short* __restrict__ A, const unsigned short* __restrict__ Bt,
    const float* __restrict__ bias, void* __restrict__ out0,
    void* __restrict__ out1, void* __restrict__ out2, int M, int N, int K) {
  __shared__ __align__(16) unsigned short As[128 * 32];
  __shared__ __align__(16) unsigned short Bs[128 * 32];
  const int tid = threadIdx.x;
  const int lane = tid & 63, w = tid >> 6;
  const int wr = w >> 1, wc = w & 1;
  const int fr = lane & 15, fg = lane >> 4;
  const int m0 = blockIdx.y * 128, n0 = blockIdx.x * 128;

  f32x4 zero = {0.f, 0.f, 0.f, 0.f};
  f32x4 acc[4][4];
#pragma unroll
  for (int m = 0; m < 4; ++m)
#pragma unroll
    for (int n = 0; n < 4; ++n) acc[m][n] = zero;

  const int c0 = tid, c1 = tid + 256;
  const unsigned short* Ab0 = A + (size_t)(m0 + (c0 >> 2)) * K + (c0 & 3) * 8;
  const unsigned short* Ab1 = A + (size_t)(m0 + (c1 >> 2)) * K + (c1 & 3) * 8;
  const unsigned short* Bb0 = Bt + (size_t)(n0 + (c0 >> 2)) * K + (c0 & 3) * 8;
  const unsigned short* Bb1 = Bt + (size_t)(n0 + (c1 >> 2)) * K + (c1 & 3) * 8;
  unsigned short* Ad0 = &As[c0 * 8];
  unsigned short* Ad1 = &As[c1 * 8];
  unsigned short* Bd0 = &Bs[c0 * 8];
  unsigned short* Bd1 = &Bs[c1 * 8];

  for (int k0 = 0; k0 < K; k0 += 32) {
    stage16(Ab0 + k0, Ad0);
    stage16(Ab1 + k0, Ad1);
    stage16(Bb0 + k0, Bd0);
    stage16(Bb1 + k0, Bd1);
    __syncthreads();
    bf16x8 af[4], bfv[4];
#pragma unroll
    for (int m = 0; m < 4; ++m)
      af[m] = *(const bf16x8*)&As[(wr * 64 + m * 16 + fr) * 32 + fg * 8];
#pragma unroll
    for (int n = 0; n < 4; ++n)
      bfv[n] = *(const bf16x8*)&Bs[(wc * 64 + n * 16 + fr) * 32 + fg * 8];
#pragma unroll
    for (int m = 0; m < 4; ++m)
#pragma unroll
      for (int n = 0; n < 4; ++n)
        acc[m][n] = __builtin_amdgcn_mfma_f32_16x16x32_bf16(af[m], bfv[n],
                                                            acc[m][n], 0, 0, 0);
    __syncthreads();
  }

#pragma unroll
  for (int m = 0; m < 4; ++m) {
#pragma unroll
    for (int n = 0; n < 4; ++n) {
      const int rb = m0 + wr * 64 + m * 16 + fg * 4;
      const int cc = n0 + wc * 64 + n * 16 + fr;
#pragma unroll
      for (int i = 0; i < 4; ++i) {
        float v = acc[m][n][i];
        const int r = rb + i;
        if (EP == 1) {
          v += bias[cc];
          v = v > 0.f ? v : 0.f;
          ((unsigned short*)out0)[(size_t)r * N + cc] = f2bf(v);
        } else if (EP == 3) {
          int p = cc >> 10, rem = cc & 1023;
          int h = rem >> 6, e = rem & 63;
          int b = r >> 10, t = r & 1023;
          unsigned short* dst =
              (p == 0) ? (unsigned short*)out0
                       : ((p == 1) ? (unsigned short*)out1 : (unsigned short*)out2);
          dst[(((size_t)(b * 16 + h) * 1024) + t) * 64 + e] = f2bf(v);
        }
      }
    }
  }
}

// ---------- 256x256 pipelined GEMM (logits): C = A * Bt^T + bias, f32 out ---
// 8 waves (2M x 4N), BK=32, 3 LDS buffers (96KB), staging 2 tiles ahead.
// Counted vmcnt(4) at tile boundaries (never 0 in steady state); raw
// s_barrier (no drain); s_setprio around MFMA clusters; 16 MFMA/barrier.
__global__ __launch_bounds__(512, 2) void k_gemm256(
    const unsigned short* __restrict__ A, const unsigned short* __restrict__ Bt,
    const float* __restrict__ bias, float* __restrict__ out,
    int M, int N, int K) {
  // buffer b: A tile at sm[b*16384 .. +8192), B tile at sm[b*16384+8192 .. )
  __shared__ __align__(16) unsigned short sm[3 * 16384];   // 96 KB
  const int tid = threadIdx.x;
  const int lane = tid & 63, wid = tid >> 6;
  const int wr = wid >> 2, wc = wid & 3;          // 2 x 4 wave grid
  const int fr = lane & 15, fg = lane >> 4;

  // XCD-aware bijective swizzle (nwg % 8 == 0 for our grids); chunk sweeps
  // M-blocks (y) of one B-panel (x) for per-XCD L2 reuse of B.
  const int nwg = gridDim.x * gridDim.y;
  int wg = blockIdx.y * gridDim.x + blockIdx.x;
  if ((nwg & 7) == 0) wg = (wg & 7) * (nwg >> 3) + (wg >> 3);
  const int m0 = (wg % gridDim.y) * 256;
  const int n0 = (wg / gridDim.y) * 256;

  const int srow = tid >> 2, scol = (tid & 3) * 8;   // staging: 16B per thread
  const int NT = K >> 5;                             // K-tiles of 32

  // stage A half-rounds rr=0,1 (rows 0-127 / 128-255); same for B
#define STAGE_A(t, b)                                                      \
  do {                                                                     \
    const unsigned short* g = A + (size_t)(m0 + srow) * K + (t) * 32 + scol; \
    stage16(g, &sm[(b) * 16384 + tid * 8]);                                \
    stage16(g + (size_t)128 * K, &sm[(b) * 16384 + 4096 + tid * 8]);       \
  } while (0)
#define STAGE_B(t, b)                                                      \
  do {                                                                     \
    const unsigned short* g = Bt + (size_t)(n0 + srow) * K + (t) * 32 + scol; \
    stage16(g, &sm[(b) * 16384 + 8192 + tid * 8]);                         \
    stage16(g + (size_t)128 * K, &sm[(b) * 16384 + 8192 + 4096 + tid * 8]); \
  } while (0)

  f32x4 zero = {0.f, 0.f, 0.f, 0.f};
  f32x4 acc[8][4];
#pragma unroll
  for (int m = 0; m < 8; ++m)
#pragma unroll
    for (int n = 0; n < 4; ++n) acc[m][n] = zero;

  // prologue: tile 0 -> buf 0, tile 1 -> buf 1; wait tile 0 (4 newest pending)
  STAGE_A(0, 0); STAGE_B(0, 0);
  STAGE_A(1, 1); STAGE_B(1, 1);
  asm volatile("s_waitcnt vmcnt(4)" ::: "memory");
  __builtin_amdgcn_s_barrier();

  int b = 0;
  for (int t = 0; t < NT; ++t) {
    const int b2 = (b + 2 >= 3) ? b - 1 : b + 2;     // (t+2) % 3
    const unsigned short* Ab = &sm[b * 16384];
    const unsigned short* Bb = &sm[b * 16384 + 8192];
    const bool pre = (t + 2) < NT;

    // ---- phase 0: stage A(t+2) | read A-frags + B0,B1 | 16 MFMA ----
    if (pre) STAGE_A(t + 2, b2);
    bf16x8 af[8], b0, b1;
#pragma unroll
    for (int m = 0; m < 8; ++m)
      af[m] = *(const bf16x8*)&Ab[(wr * 128 + m * 16 + fr) * 32 + fg * 8];
    b0 = *(const bf16x8*)&Bb[(wc * 64 + 0 * 16 + fr) * 32 + fg * 8];
    b1 = *(const bf16x8*)&Bb[(wc * 64 + 1 * 16 + fr) * 32 + fg * 8];
    __builtin_amdgcn_s_setprio(1);
#pragma unroll
    for (int m = 0; m < 8; ++m) {
      acc[m][0] = __builtin_amdgcn_mfma_f32_16x16x32_bf16(af[m], b0, acc[m][0], 0, 0, 0);
      acc[m][1] = __builtin_amdgcn_mfma_f32_16x16x32_bf16(af[m], b1, acc[m][1], 0, 0, 0);
    }
    __builtin_amdgcn_s_setprio(0);
    __builtin_amdgcn_s_barrier();

    // ---- phase 1: stage B(t+2) | read B2,B3 | 16 MFMA ----
    if (pre) STAGE_B(t + 2, b2);
    bf16x8 b2f = *(const bf16x8*)&Bb[(wc * 64 + 2 * 16 + fr) * 32 + fg * 8];
    bf16x8 b3f = *(const bf16x8*)&Bb[(wc * 64 + 3 * 16 + fr) * 32 + fg * 8];
    __builtin_amdgcn_s_setprio(1);
#pragma unroll
    for (int m = 0; m < 8; ++m) {
      acc[m][2] = __builtin_amdgcn_mfma_f32_16x16x32_bf16(af[m], b2f, acc[m][2], 0, 0, 0);
      acc[m][3] = __builtin_amdgcn_mfma_f32_16x16x32_bf16(af[m], b3f, acc[m][3], 0, 0, 0);
    }
    __builtin_amdgcn_s_setprio(0);

    // tile boundary: guard tile t+1 (4 newest outstanding = tile t+2's loads)
    if (t < NT - 2) {
      asm volatile("s_waitcnt vmcnt(4)" ::: "memory");
    } else {
      asm volatile("s_waitcnt vmcnt(0)" ::: "memory");
    }
    __builtin_amdgcn_s_barrier();
    b = (b + 1 >= 3) ? 0 : b + 1;
  }
#undef STAGE_A
#undef STAGE_B

  // epilogue: bias + f32 store
#pragma unroll
  for (int m = 0; m < 8; ++m) {
#pragma unroll
    for (int n = 0; n < 4; ++n) {
      const int rb = m0 + wr * 128 + m * 16 + fg * 4;
      const int cc = n0 + wc * 64 + n * 16 + fr;
      const float bs = bias[cc];
#pragma unroll
      for (int i = 0; i < 4; ++i)
        out[(size_t)(rb + i) * N + cc] = acc[m][n][i] + bs;
    }
  }
}

// ---------------- fused causal flash attention ------------------------------
__global__ __launch_bounds__(256) void k_attn(
    const unsigned short* __restrict__ qb, const unsigned short* __restrict__ kb,
    const unsigned short* __restrict__ vb, unsigned short* __restrict__ attx) {
  __shared__ __align__(16) unsigned short Klds[64][72];
  __shared__ __align__(16) unsigned short Vt[64][72];
  __shared__ __align__(16) unsigned short Plds[4][16][72];
  const int qt = blockIdx.x;
  const int bh = blockIdx.y;
  const int tid = threadIdx.x;
  const int w = tid >> 6, lane = tid & 63;
  const int fr = lane & 15, g = lane >> 4;
  const size_t base = (size_t)bh * (1024 * 64);
  const int q0 = qt * 64 + w * 16;
  const int q_abs = q0 + fr;

  bf16x8 qf[2];
#pragma unroll
  for (int t = 0; t < 2; ++t)
    qf[t] = *(const bf16x8*)&qb[base + (size_t)(q0 + fr) * 64 + t * 32 + g * 8];

  f32x4 zero = {0.f, 0.f, 0.f, 0.f};
  f32x4 o[4];
#pragma unroll
  for (int hb = 0; hb < 4; ++hb) o[hb] = zero;
  float m_s = -3.0e38f, l_s = 0.f;

  for (int jt = 0; jt <= qt; ++jt) {
    const int kvb = jt * 64;
#pragma unroll
    for (int it = 0; it < 2; ++it) {
      int c = tid + it * 256;
      int r = c >> 3, e0 = (c & 7) * 8;
      uint4 kd = *(const uint4*)&kb[base + (size_t)(kvb + r) * 64 + e0];
      *(uint4*)&Klds[r][e0] = kd;
      uint4 vd = *(const uint4*)&vb[base + (size_t)(kvb + r) * 64 + e0];
      const unsigned short* vs = (const unsigned short*)&vd;
#pragma unroll
      for (int j = 0; j < 8; ++j) Vt[e0 + j][r] = vs[j];
    }
    __syncthreads();

    f32x4 st[4];
#pragma unroll
    for (int f = 0; f < 4; ++f) {
      st[f] = zero;
#pragma unroll
      for (int t = 0; t < 2; ++t) {
        bf16x8 kf = *(const bf16x8*)&Klds[f * 16 + fr][t * 32 + g * 8];
        st[f] = __builtin_amdgcn_mfma_f32_16x16x32_bf16(kf, qf[t], st[f], 0, 0, 0);
      }
    }
    float sv[4][4];
    float tm = -3.0e38f;
#pragma unroll
    for (int f = 0; f < 4; ++f)
#pragma unroll
      for (int i = 0; i < 4; ++i) {
        int kv = kvb + f * 16 + g * 4 + i;
        float s = st[f][i] * 0.125f;
        if (kv > q_abs) s = -3.0e38f;
        sv[f][i] = s;
        tm = fmaxf(tm, s);
      }
    tm = fmaxf(tm, __shfl_xor(tm, 16));
    tm = fmaxf(tm, __shfl_xor(tm, 32));
    float mnew = fmaxf(m_s, tm);
    float scale = expf(m_s - mnew);
    float lsum = 0.f;
#pragma unroll
    for (int f = 0; f < 4; ++f)
#pragma unroll
      for (int i = 0; i < 4; ++i) {
        float pv = expf(sv[f][i] - mnew);
        lsum += pv;
        Plds[w][fr][f * 16 + g * 4 + i] = f2bf(pv);
      }
    lsum += __shfl_xor(lsum, 16);
    lsum += __shfl_xor(lsum, 32);
    l_s = l_s * scale + lsum;
    m_s = mnew;
#pragma unroll
    for (int i = 0; i < 4; ++i) {
      float sc = __shfl(scale, g * 4 + i);
#pragma unroll
      for (int hb = 0; hb < 4; ++hb) o[hb][i] *= sc;
    }
    __syncthreads();
#pragma unroll
    for (int t = 0; t < 2; ++t) {
      bf16x8 pf = *(const bf16x8*)&Plds[w][fr][t * 32 + g * 8];
#pragma unroll
      for (int hb = 0; hb < 4; ++hb) {
        bf16x8 vf = *(const bf16x8*)&Vt[hb * 16 + fr][t * 32 + g * 8];
        o[hb] = __builtin_amdgcn_mfma_f32_16x16x32_bf16(pf, vf, o[hb], 0, 0, 0);
      }
    }
    __syncthreads();
  }

  const float inv = 1.f / l_s;
  const int b = bh >> 4, h = bh & 15;
#pragma unroll
  for (int i = 0; i < 4; ++i) {
    float sc = __shfl(inv, g * 4 + i);
    int trow = q0 + g * 4 + i;
    size_t rowoff = ((size_t)(b * 1024 + trow)) * 1024 + h * 64;
#pragma unroll
    for (int hb = 0; hb < 4; ++hb)
      attx[rowoff + hb * 16 + fr] = f2bf(o[hb][i] * sc);
  }
}

// ------------------------------- launch -------------------------------------
extern "C" void kernel_launch(void* const* d_in, const int* in_sizes, int n_in,
                              void* d_out, int out_size, void* d_ws,
                              size_t ws_size, hipStream_t stream) {
  const int* idx = (const int*)d_in[0];
  const float* tok = (const float*)d_in[1];
  const float* pos = (const float*)d_in[2];
  const float* Wq = (const float*)d_in[3];
  const float* Wk = (const float*)d_in[4];
  const float* Wv = (const float*)d_in[5];
  const float* W1 = (const float*)d_in[6];
  const float* b1 = (const float*)d_in[7];
  const float* W2 = (const float*)d_in[8];
  const float* b2 = (const float*)d_in[9];
  const float* Wout = (const float*)d_in[10];
  const float* bout = (const float*)d_in[11];
  float* out = (float*)d_out;

  char* ws = (char*)d_ws;
  unsigned short* xb    = (unsigned short*)(ws + 0);
  unsigned short* wqkvT = (unsigned short*)(ws + 8388608);
  unsigned short* w1T   = (unsigned short*)(ws + 14680064);
  unsigned short* w2T   = (unsigned short*)(ws + 16777216);
  unsigned short* woutT = (unsigned short*)(ws + 18874368);
  unsigned short* qbuf  = (unsigned short*)(ws + 84410368);
  unsigned short* kbuf  = (unsigned short*)(ws + 92798976);
  unsigned short* vbuf  = (unsigned short*)(ws + 101187584);
  unsigned short* attx  = (unsigned short*)(ws + 109576192);
  unsigned short* h1    = (unsigned short*)(ws + 117964800);
  unsigned short* h2    = xb;

  k_embed<<<4096, 256, 0, stream>>>(idx, tok, pos, xb);
  k_pack_qkv<<<768, 256, 0, stream>>>(Wq, Wk, Wv, wqkvT);
  k_transpose<<<dim3(16, 16), 256, 0, stream>>>(W1, w1T, 1024, 1024);
  k_transpose<<<dim3(16, 16), 256, 0, stream>>>(W2, w2T, 1024, 1024);
  k_transpose<<<dim3(500, 16), 256, 0, stream>>>(Wout, woutT, 1024, 32000);

  k_gemm<3><<<dim3(24, 32), 256, 0, stream>>>(xb, wqkvT, nullptr, qbuf, kbuf,
                                              vbuf, 4096, 3072, 1024);
  k_attn<<<dim3(16, 64), 256, 0, stream>>>(qbuf, kbuf, vbuf, attx);
  k_gemm<1><<<dim3(8, 32), 256, 0, stream>>>(attx, w1T, b1, h1, nullptr,
                                             nullptr, 4096, 1024, 1024);
  k_gemm<1><<<dim3(8, 32), 256, 0, stream>>>(h1, w2T, b2, h2, nullptr, nullptr,
                                             4096, 1024, 1024);
  // logits: 256x256 pipelined kernel, grid (N/256, M/256) = (125, 16)
  k_gemm256<<<dim3(125, 16), 512, 0, stream>>>(h2, woutT, bout, out, 4096,
                                               32000, 1024);
}